// Round 1
// baseline (681.180 us; speedup 1.0000x reference)
//
#include <hip/hip_runtime.h>

// StereoDenoiser: disp = clip(depth*128, 0, 128); bilinear horizontal warp of
// img_r by -disp and img_l by +disp (border clamp), average with the direct
// image. Shapes fixed: B=8, C=3, H=1024, W=1920, fp32 in/out.
// Outputs concatenated: [denoised_l (B,C,H,W), denoised_r (B,C,H,W)].

constexpr int B = 8, C = 3, H = 1024, W = 1920;
constexpr int HW  = H * W;
constexpr int CHW = C * HW;
constexpr int W4  = W / 4;
constexpr long OUT_HALF = (long)B * CHW;
constexpr float MAX_DISP = 128.0f;

__global__ __launch_bounds__(256) void stereo_denoise(
    const float* __restrict__ img_l, const float* __restrict__ img_r,
    const float* __restrict__ depth, float* __restrict__ out)
{
    int tid = blockIdx.x * blockDim.x + threadIdx.x;
    if (tid >= B * H * W4) return;

    int w4 = tid % W4;
    int bh = tid / W4;          // b*H + h
    int b  = bh / H;
    int w  = w4 * 4;
    long row = (long)bh * W;    // = b*HW + h*W  (valid for depth [B,1,H,W])

    // disparity for 4 pixels (vector load, aligned: row and w are mult. of 4)
    const float4 d4 = *reinterpret_cast<const float4*>(depth + row + w);
    float dispv[4] = {d4.x, d4.y, d4.z, d4.w};

    int   i0m[4], i1m[4], i0p[4], i1p[4];
    float wm[4], wp[4];
#pragma unroll
    for (int j = 0; j < 4; ++j) {
        float d  = fminf(fmaxf(dispv[j] * MAX_DISP, 0.0f), MAX_DISP);
        float xw = (float)(w + j);
        // x - disp: gather source for warped_r (from img_r)
        float xm = fminf(fmaxf(xw - d, 0.0f), (float)(W - 1));
        // x + disp: gather source for warped_l (from img_l)
        float xp = fminf(fmaxf(xw + d, 0.0f), (float)(W - 1));
        float fm  = floorf(xm);
        float fpp = floorf(xp);
        i0m[j] = (int)fm;  i1m[j] = min(i0m[j] + 1, W - 1);  wm[j] = xm - fm;
        i0p[j] = (int)fpp; i1p[j] = min(i0p[j] + 1, W - 1);  wp[j] = xp - fpp;
    }

    // plane-0 row base for this (b,h): b*CHW + h*W = row + 2*b*HW
    long base = row + (long)(2 * b) * HW;

#pragma unroll
    for (int c = 0; c < C; ++c) {
        const float* pl = img_l + base + (long)c * HW;  // row start, index by column
        const float* pr = img_r + base + (long)c * HW;

        float4 vl = *reinterpret_cast<const float4*>(pl + w);
        float4 vr = *reinterpret_cast<const float4*>(pr + w);
        const float* vlp = &vl.x;
        const float* vrp = &vr.x;

        float4 ol, orr;
        float* olp = &ol.x;
        float* orp = &orr.x;
#pragma unroll
        for (int j = 0; j < 4; ++j) {
            float r0 = pr[i0m[j]], r1 = pr[i1m[j]];
            float warped_r = r0 * (1.0f - wm[j]) + r1 * wm[j];
            float l0 = pl[i0p[j]], l1 = pl[i1p[j]];
            float warped_l = l0 * (1.0f - wp[j]) + l1 * wp[j];
            olp[j] = (vlp[j] + warped_r) * 0.5f;   // denoised_l
            orp[j] = (vrp[j] + warped_l) * 0.5f;   // denoised_r
        }
        long oidx = base + (long)c * HW + w;
        *reinterpret_cast<float4*>(out + oidx)            = ol;
        *reinterpret_cast<float4*>(out + OUT_HALF + oidx) = orr;
    }
}

extern "C" void kernel_launch(void* const* d_in, const int* in_sizes, int n_in,
                              void* d_out, int out_size, void* d_ws, size_t ws_size,
                              hipStream_t stream) {
    const float* img_l = (const float*)d_in[0];
    const float* img_r = (const float*)d_in[1];
    const float* depth = (const float*)d_in[2];
    float* out = (float*)d_out;

    const int total = B * H * W4;          // 3,932,160 threads
    const int block = 256;
    const int grid  = (total + block - 1) / block;
    stereo_denoise<<<grid, block, 0, stream>>>(img_l, img_r, depth, out);
}